// Round 1
// baseline (190.628 us; speedup 1.0000x reference)
//
#include <hip/hip_runtime.h>
#include <hip/hip_bf16.h>
#include <math.h>

// B=256, C=4, N=64, F=256, OC=8, OF=256
// Outputs: out (256*2048 f32) then adj (256*4*256*256 f32), concatenated in d_out.

typedef __bf16 bf16x8 __attribute__((ext_vector_type(8)));
typedef float f32x4 __attribute__((ext_vector_type(4)));

#define NB 256        // batch
#define NC 4
#define NN 64
#define NF 256
#define KK 2048       // 2C*F
#define NO 2048       // OC*OF

// ---------------- Kernel 1: s1[b], s2[b,n] ----------------
// s1[b] = sum_f (sum_c x[b,c,f]) * (sum_c W1[c,f]) ; s2 same with neighbor/W2.
__global__ __launch_bounds__(256) void k_scores(
    const float* __restrict__ x, const float* __restrict__ nb,
    const float* __restrict__ W1, const float* __restrict__ W2,
    float* __restrict__ s1, float* __restrict__ s2)
{
  __shared__ float red[4];
  int t = threadIdx.x;
  int gid = blockIdx.x;
  float val;
  if (gid < NB * NN) {
    float w = W2[t] + W2[256 + t] + W2[512 + t] + W2[768 + t];
    const float* p = nb + (size_t)gid * 1024;
    val = w * (p[t] + p[256 + t] + p[512 + t] + p[768 + t]);
  } else {
    int b = gid - NB * NN;
    float w = W1[t] + W1[256 + t] + W1[512 + t] + W1[768 + t];
    const float* p = x + (size_t)b * 1024;
    val = w * (p[t] + p[256 + t] + p[512 + t] + p[768 + t]);
  }
  for (int off = 32; off > 0; off >>= 1) val += __shfl_down(val, off);
  int wid = t >> 6;
  if ((t & 63) == 0) red[wid] = val;
  __syncthreads();
  if (t == 0) {
    float s = red[0] + red[1] + red[2] + red[3];
    if (gid < NB * NN) s2[gid] = s;
    else s1[gid - NB * NN] = s;
  }
}

// ---------------- Kernel 2: adj + h ----------------
// One block per (b,c). fadj_sym is symmetric -> column-normalizer == row sum.
// Thread j owns column j: pass1 rowsum, pass2 write adj[i][j] (coalesced) and
// accumulate h[j] = sum_i g(i,j)*inv[i]*x[i].
__global__ __launch_bounds__(256) void k_adj(
    const float* __restrict__ x, const float* __restrict__ nb,
    const float* __restrict__ s1, const float* __restrict__ s2,
    float* __restrict__ adj, float* __restrict__ h)
{
  __shared__ float xs[256], ns[256], inv[256], wsh[64];
  int j = threadIdx.x;
  int blk = blockIdx.x;
  int b = blk >> 2, c = blk & 3;

  // softmax over n, computed by wave 0
  if (j < 64) {
    float v = s1[b] * s2[b * 64 + j];
    float m = v;
    for (int off = 32; off > 0; off >>= 1) m = fmaxf(m, __shfl_xor(m, off));
    float e = expf(v - m);
    float s = e;
    for (int off = 32; off > 0; off >>= 1) s += __shfl_xor(s, off);
    wsh[j] = e / s;
  }
  __syncthreads();

  // nw[j] = sum_n w[n] * neighbor[b,n,c,j]  (coalesced 1KB per iter)
  float acc = 0.f;
  const float* pb = nb + (size_t)b * 64 * 1024 + c * 256 + j;
  #pragma unroll 8
  for (int n = 0; n < 64; ++n) acc = fmaf(wsh[n], pb[(size_t)n * 1024], acc);
  ns[j] = acc;
  xs[j] = x[(size_t)blk * 256 + j];
  __syncthreads();

  float xj = xs[j], nj = ns[j];
  float rs = 0.f;
  #pragma unroll 8
  for (int i = 0; i < 256; ++i) {
    float v = fmaf(xj, ns[i], xs[i] * nj);           // g[j][i] arg (symmetric)
    float r = sqrtf(fmaxf(fabsf(v), 1e-8f));
    rs += (v != 0.f) ? r : 0.f;                      // |sgnroot(v)|, sign(0)=0
  }
  inv[j] = 1.f / (rs + 1e-7f);
  __syncthreads();

  float invj = inv[j];
  float hacc = 0.f;
  float* ab = adj + (size_t)blk * 65536;
  #pragma unroll 4
  for (int i = 0; i < 256; ++i) {
    float v = fmaf(xs[i], nj, xj * ns[i]);           // g[i][j] arg
    float r = sqrtf(fmaxf(fabsf(v), 1e-8f));
    float g = (v > 0.f) ? r : ((v < 0.f) ? -r : 0.f);
    ab[i * 256 + j] = g * invj;                      // adj[i][j], coalesced in j
    hacc = fmaf(g * inv[i], xs[i], hacc);            // h[j] += g[j][i]*inv[i]*x[i]
  }
  h[(size_t)blk * 256 + j] = hacc;
}

// ---------------- Kernel 3: out = Z @ Wc^T via bf16 MFMA ----------------
// Z[b,k] = (k<1024) ? h[b*1024+k] : x[b*1024+k-1024]; Wc row-major [2048][2048].
__device__ inline bf16x8 cvt8_p(const float* p) {
  const float4* q = reinterpret_cast<const float4*>(p);
  float4 a = q[0], bq = q[1];
  bf16x8 r;
  r[0] = (__bf16)a.x;  r[1] = (__bf16)a.y;  r[2] = (__bf16)a.z;  r[3] = (__bf16)a.w;
  r[4] = (__bf16)bq.x; r[5] = (__bf16)bq.y; r[6] = (__bf16)bq.z; r[7] = (__bf16)bq.w;
  return r;
}

__global__ __launch_bounds__(256) void k_gemm(
    const float* __restrict__ h, const float* __restrict__ x,
    const float* __restrict__ Wc, float* __restrict__ out)
{
  int tid = threadIdx.x;
  int wave = tid >> 6, lane = tid & 63;
  int g = lane >> 4, r = lane & 15;
  int bm = blockIdx.x & 3, bn = blockIdx.x >> 2;   // 4 m-blocks x 64 n-blocks
  int m0 = bm * 64 + wave * 16;
  int n0 = bn * 32;
  int arow = m0 + r;
  int koff = g * 8;

  const float* za = h + (size_t)arow * 1024 + koff;       // k in [0,1024)
  const float* zb = x + (size_t)arow * 1024 + koff;       // k in [1024,2048)
  const float* w0 = Wc + (size_t)(n0 + r) * 2048 + koff;
  const float* w1 = Wc + (size_t)(n0 + 16 + r) * 2048 + koff;

  f32x4 acc0 = {0.f, 0.f, 0.f, 0.f}, acc1 = {0.f, 0.f, 0.f, 0.f};
  #pragma unroll 4
  for (int ks = 0; ks < 32; ++ks) {
    bf16x8 a  = cvt8_p(za + ks * 32);
    bf16x8 b0 = cvt8_p(w0 + ks * 32);
    bf16x8 b1 = cvt8_p(w1 + ks * 32);
    acc0 = __builtin_amdgcn_mfma_f32_16x16x32_bf16(a, b0, acc0, 0, 0, 0);
    acc1 = __builtin_amdgcn_mfma_f32_16x16x32_bf16(a, b1, acc1, 0, 0, 0);
  }
  #pragma unroll 4
  for (int ks = 0; ks < 32; ++ks) {
    bf16x8 a  = cvt8_p(zb + ks * 32);
    bf16x8 b0 = cvt8_p(w0 + 1024 + ks * 32);
    bf16x8 b1 = cvt8_p(w1 + 1024 + ks * 32);
    acc0 = __builtin_amdgcn_mfma_f32_16x16x32_bf16(a, b0, acc0, 0, 0, 0);
    acc1 = __builtin_amdgcn_mfma_f32_16x16x32_bf16(a, b1, acc1, 0, 0, 0);
  }
  #pragma unroll
  for (int q = 0; q < 4; ++q) {
    int row = m0 + g * 4 + q;                 // D: row=(lane>>4)*4+reg, col=lane&15
    out[(size_t)row * 2048 + n0 + r]      = acc0[q];
    out[(size_t)row * 2048 + n0 + 16 + r] = acc1[q];
  }
}

extern "C" void kernel_launch(void* const* d_in, const int* in_sizes, int n_in,
                              void* d_out, int out_size, void* d_ws, size_t ws_size,
                              hipStream_t stream) {
  const float* x  = (const float*)d_in[0];
  const float* nb = (const float*)d_in[1];
  const float* W1 = (const float*)d_in[2];
  const float* W2 = (const float*)d_in[3];
  const float* Wc = (const float*)d_in[4];
  float* out = (float*)d_out;
  float* adj = out + (size_t)NB * NO;          // 524288 floats in, 67108864 floats
  float* hws = (float*)d_ws;                   // [0, 1MB): h (256*1024 f32)
  float* s1  = hws + 262144;                   // 256 f32
  float* s2  = s1 + 256;                       // 16384 f32

  k_scores<<<NB * NN + NB, 256, 0, stream>>>(x, nb, W1, W2, s1, s2);
  k_adj<<<NB * NC, 256, 0, stream>>>(x, nb, s1, s2, adj, hws);
  k_gemm<<<256, 256, 0, stream>>>(hws, x, Wc, out);
}

// Round 2
// 139.464 us; speedup vs baseline: 1.3669x; 1.3669x over previous
//
#include <hip/hip_runtime.h>
#include <hip/hip_bf16.h>
#include <math.h>

// B=256, C=4, N=64, F=256, OC=8, OF=256
// d_out = out (256*2048 f32) then adj (256*4*256*256 f32).

typedef __bf16 bf16x8 __attribute__((ext_vector_type(8)));
typedef __bf16 bf16x4 __attribute__((ext_vector_type(4)));
typedef float f32x4 __attribute__((ext_vector_type(4)));

#define NB 256
#define NC 4
#define NN 64
#define NF 256
#define NO 2048

// ---------------- Kernel 1: s1[b], s2[b,n] ----------------
__global__ __launch_bounds__(256) void k_scores(
    const float* __restrict__ x, const float* __restrict__ nb,
    const float* __restrict__ W1, const float* __restrict__ W2,
    float* __restrict__ s1, float* __restrict__ s2)
{
  __shared__ float red[4];
  int t = threadIdx.x;
  int gid = blockIdx.x;
  float val;
  if (gid < NB * NN) {
    float w = W2[t] + W2[256 + t] + W2[512 + t] + W2[768 + t];
    const float* p = nb + (size_t)gid * 1024;
    val = w * (p[t] + p[256 + t] + p[512 + t] + p[768 + t]);
  } else {
    int b = gid - NB * NN;
    float w = W1[t] + W1[256 + t] + W1[512 + t] + W1[768 + t];
    const float* p = x + (size_t)b * 1024;
    val = w * (p[t] + p[256 + t] + p[512 + t] + p[768 + t]);
  }
  for (int off = 32; off > 0; off >>= 1) val += __shfl_down(val, off);
  int wid = t >> 6;
  if ((t & 63) == 0) red[wid] = val;
  __syncthreads();
  if (t == 0) {
    float s = red[0] + red[1] + red[2] + red[3];
    if (gid < NB * NN) s2[gid] = s;
    else s1[gid - NB * NN] = s;
  }
}

// ---------------- Kernel 2: bf16 pre-conversion ----------------
// Wc (1048576 float4s) -> Wcb ; x (65536 float4s) -> zbf[b][1024 + r]
__global__ __launch_bounds__(256) void k_cvt(
    const float* __restrict__ Wc, const float* __restrict__ x,
    __hip_bfloat16* __restrict__ Wcb, __hip_bfloat16* __restrict__ zbf)
{
  int idx = blockIdx.x * 256 + threadIdx.x;
  if (idx < 1048576) {
    float4 v = ((const float4*)Wc)[idx];
    bf16x4 o = { (__bf16)v.x, (__bf16)v.y, (__bf16)v.z, (__bf16)v.w };
    ((bf16x4*)Wcb)[idx] = o;
  } else {
    int i = idx - 1048576;                    // float4 index into x
    int e = i * 4;
    int b = e >> 10, r = e & 1023;
    float4 v = ((const float4*)x)[i];
    bf16x4 o = { (__bf16)v.x, (__bf16)v.y, (__bf16)v.z, (__bf16)v.w };
    *(bf16x4*)(zbf + (size_t)b * 2048 + 1024 + r) = o;
  }
}

// ---------------- Kernel 3: adj + h ----------------
// One block per (b,c). fadj_sym symmetric -> column normalizer == row sum.
// Thread t: wave w=t>>6 owns rows i=w*64..w*64+63; lane l owns cols 4l..4l+3.
__device__ inline float sgnroot(float v) {
  float r = sqrtf(fmaxf(fabsf(v), 1e-8f));
  return (v > 0.f) ? r : ((v < 0.f) ? -r : 0.f);
}

__global__ __launch_bounds__(256) void k_adj(
    const float* __restrict__ x, const float* __restrict__ nb,
    const float* __restrict__ s1, const float* __restrict__ s2,
    float* __restrict__ adj, float* __restrict__ hf,
    __hip_bfloat16* __restrict__ zbf)
{
  __shared__ float xs[256], ns[256], invs[256], wsh[64];
  __shared__ float part[4][256];
  int t = threadIdx.x;
  int w = t >> 6, l = t & 63;
  int blk = blockIdx.x;
  int b = blk >> 2, c = blk & 3;

  if (t < 64) {
    float v = s1[b] * s2[b * 64 + t];
    float m = v;
    for (int off = 32; off > 0; off >>= 1) m = fmaxf(m, __shfl_xor(m, off));
    float e = expf(v - m);
    float s = e;
    for (int off = 32; off > 0; off >>= 1) s += __shfl_xor(s, off);
    wsh[t] = e / s;
  }
  __syncthreads();

  // nw[t] = sum_n w[n] * neighbor[b,n,c,t]
  float acc = 0.f;
  const float* pb = nb + (size_t)b * 65536 + c * 256 + t;
  #pragma unroll 8
  for (int n = 0; n < 64; ++n) acc = fmaf(wsh[n], pb[(size_t)n * 1024], acc);
  ns[t] = acc;
  xs[t] = x[(size_t)blk * 256 + t];
  __syncthreads();

  int j0 = l * 4;
  float4 xv = *(const float4*)&xs[j0];
  float4 nv = *(const float4*)&ns[j0];
  int i0 = w * 64;

  // pass 1: column sums of |g| (g symmetric => equals row sums)
  float4 cs = {0.f, 0.f, 0.f, 0.f};
  #pragma unroll 4
  for (int ii = 0; ii < 64; ++ii) {
    int i = i0 + ii;
    float xi = xs[i], ni = ns[i];
    float v0 = fmaf(xi, nv.x, xv.x * ni);
    float v1 = fmaf(xi, nv.y, xv.y * ni);
    float v2 = fmaf(xi, nv.z, xv.z * ni);
    float v3 = fmaf(xi, nv.w, xv.w * ni);
    cs.x += (v0 != 0.f) ? sqrtf(fmaxf(fabsf(v0), 1e-8f)) : 0.f;
    cs.y += (v1 != 0.f) ? sqrtf(fmaxf(fabsf(v1), 1e-8f)) : 0.f;
    cs.z += (v2 != 0.f) ? sqrtf(fmaxf(fabsf(v2), 1e-8f)) : 0.f;
    cs.w += (v3 != 0.f) ? sqrtf(fmaxf(fabsf(v3), 1e-8f)) : 0.f;
  }
  *(float4*)&part[w][j0] = cs;
  __syncthreads();
  invs[t] = 1.f / (part[0][t] + part[1][t] + part[2][t] + part[3][t] + 1e-7f);
  __syncthreads();

  float4 iv = *(const float4*)&invs[j0];
  float4 ha = {0.f, 0.f, 0.f, 0.f};
  float* ab = adj + (size_t)blk * 65536;
  #pragma unroll 4
  for (int ii = 0; ii < 64; ++ii) {
    int i = i0 + ii;
    float xi = xs[i], ni = ns[i];
    float pix = invs[i] * xi;
    float g0 = sgnroot(fmaf(xi, nv.x, xv.x * ni));
    float g1 = sgnroot(fmaf(xi, nv.y, xv.y * ni));
    float g2 = sgnroot(fmaf(xi, nv.z, xv.z * ni));
    float g3 = sgnroot(fmaf(xi, nv.w, xv.w * ni));
    float4 o = { g0 * iv.x, g1 * iv.y, g2 * iv.z, g3 * iv.w };
    *(float4*)&ab[(size_t)i * 256 + j0] = o;
    ha.x = fmaf(g0, pix, ha.x);
    ha.y = fmaf(g1, pix, ha.y);
    ha.z = fmaf(g2, pix, ha.z);
    ha.w = fmaf(g3, pix, ha.w);
  }
  __syncthreads();
  *(float4*)&part[w][j0] = ha;
  __syncthreads();
  float hsum = part[0][t] + part[1][t] + part[2][t] + part[3][t];
  if (zbf) zbf[(size_t)b * 2048 + c * 256 + t] = __float2bfloat16(hsum);
  else     hf[(size_t)blk * 256 + t] = hsum;
}

// ---------------- Kernel 4: out = Z @ Wc^T (bf16 MFMA, pure loads) --------
__global__ __launch_bounds__(256) void k_gemm(
    const __hip_bfloat16* __restrict__ zb, const __hip_bfloat16* __restrict__ Wcb,
    float* __restrict__ out)
{
  int tid = threadIdx.x;
  int wave = tid >> 6, lane = tid & 63;
  int g = lane >> 4, r = lane & 15;
  int bm = blockIdx.x & 3, bn = blockIdx.x >> 2;
  int m0 = bm * 64 + wave * 16;
  int n0 = bn * 32;

  const bf16x8* pa  = (const bf16x8*)(zb  + (size_t)(m0 + r) * 2048 + g * 8);
  const bf16x8* pb0 = (const bf16x8*)(Wcb + (size_t)(n0 + r) * 2048 + g * 8);
  const bf16x8* pb1 = (const bf16x8*)(Wcb + (size_t)(n0 + 16 + r) * 2048 + g * 8);

  f32x4 acc0 = {0.f, 0.f, 0.f, 0.f}, acc1 = {0.f, 0.f, 0.f, 0.f};
  #pragma unroll 4
  for (int ks = 0; ks < 64; ++ks) {
    bf16x8 a  = pa[ks * 4];
    bf16x8 b0 = pb0[ks * 4];
    bf16x8 b1 = pb1[ks * 4];
    acc0 = __builtin_amdgcn_mfma_f32_16x16x32_bf16(a, b0, acc0, 0, 0, 0);
    acc1 = __builtin_amdgcn_mfma_f32_16x16x32_bf16(a, b1, acc1, 0, 0, 0);
  }
  #pragma unroll
  for (int q = 0; q < 4; ++q) {
    int row = m0 + g * 4 + q;
    out[(size_t)row * 2048 + n0 + r]      = acc0[q];
    out[(size_t)row * 2048 + n0 + 16 + r] = acc1[q];
  }
}

// ---------------- Fallback GEMM (f32 inputs, cvt in loop) ----------------
__device__ inline bf16x8 cvt8_p(const float* p) {
  const float4* q = reinterpret_cast<const float4*>(p);
  float4 a = q[0], bq = q[1];
  bf16x8 r;
  r[0] = (__bf16)a.x;  r[1] = (__bf16)a.y;  r[2] = (__bf16)a.z;  r[3] = (__bf16)a.w;
  r[4] = (__bf16)bq.x; r[5] = (__bf16)bq.y; r[6] = (__bf16)bq.z; r[7] = (__bf16)bq.w;
  return r;
}

__global__ __launch_bounds__(256) void k_gemm_f32(
    const float* __restrict__ h, const float* __restrict__ x,
    const float* __restrict__ Wc, float* __restrict__ out)
{
  int tid = threadIdx.x;
  int wave = tid >> 6, lane = tid & 63;
  int g = lane >> 4, r = lane & 15;
  int bm = blockIdx.x & 3, bn = blockIdx.x >> 2;
  int m0 = bm * 64 + wave * 16;
  int n0 = bn * 32;
  int arow = m0 + r;
  int koff = g * 8;

  const float* za = h + (size_t)arow * 1024 + koff;
  const float* zb = x + (size_t)arow * 1024 + koff;
  const float* w0 = Wc + (size_t)(n0 + r) * 2048 + koff;
  const float* w1 = Wc + (size_t)(n0 + 16 + r) * 2048 + koff;

  f32x4 acc0 = {0.f, 0.f, 0.f, 0.f}, acc1 = {0.f, 0.f, 0.f, 0.f};
  #pragma unroll 4
  for (int ks = 0; ks < 32; ++ks) {
    bf16x8 a  = cvt8_p(za + ks * 32);
    bf16x8 b0 = cvt8_p(w0 + ks * 32);
    bf16x8 b1 = cvt8_p(w1 + ks * 32);
    acc0 = __builtin_amdgcn_mfma_f32_16x16x32_bf16(a, b0, acc0, 0, 0, 0);
    acc1 = __builtin_amdgcn_mfma_f32_16x16x32_bf16(a, b1, acc1, 0, 0, 0);
  }
  #pragma unroll 4
  for (int ks = 0; ks < 32; ++ks) {
    bf16x8 a  = cvt8_p(zb + ks * 32);
    bf16x8 b0 = cvt8_p(w0 + 1024 + ks * 32);
    bf16x8 b1 = cvt8_p(w1 + 1024 + ks * 32);
    acc0 = __builtin_amdgcn_mfma_f32_16x16x32_bf16(a, b0, acc0, 0, 0, 0);
    acc1 = __builtin_amdgcn_mfma_f32_16x16x32_bf16(a, b1, acc1, 0, 0, 0);
  }
  #pragma unroll
  for (int q = 0; q < 4; ++q) {
    int row = m0 + g * 4 + q;
    out[(size_t)row * 2048 + n0 + r]      = acc0[q];
    out[(size_t)row * 2048 + n0 + 16 + r] = acc1[q];
  }
}

extern "C" void kernel_launch(void* const* d_in, const int* in_sizes, int n_in,
                              void* d_out, int out_size, void* d_ws, size_t ws_size,
                              hipStream_t stream) {
  const float* x  = (const float*)d_in[0];
  const float* nb = (const float*)d_in[1];
  const float* W1 = (const float*)d_in[2];
  const float* W2 = (const float*)d_in[3];
  const float* Wc = (const float*)d_in[4];
  float* out = (float*)d_out;
  float* adj = out + (size_t)NB * NO;

  char* ws = (char*)d_ws;
  const size_t ZBF_B = 1048576;       // 256*2048 bf16
  const size_t WCB_B = 8388608;       // 2048*2048 bf16
  bool fast = ws_size >= ZBF_B + WCB_B + 66560;

  if (fast) {
    __hip_bfloat16* zbf = (__hip_bfloat16*)ws;
    __hip_bfloat16* Wcb = (__hip_bfloat16*)(ws + ZBF_B);
    float* s1 = (float*)(ws + ZBF_B + WCB_B);
    float* s2 = s1 + 256;
    k_scores<<<NB * NN + NB, 256, 0, stream>>>(x, nb, W1, W2, s1, s2);
    k_cvt<<<4352, 256, 0, stream>>>(Wc, x, Wcb, zbf);
    k_adj<<<NB * NC, 256, 0, stream>>>(x, nb, s1, s2, adj, nullptr, zbf);
    k_gemm<<<256, 256, 0, stream>>>(zbf, Wcb, out);
  } else {
    float* hws = (float*)d_ws;
    float* s1  = hws + 262144;
    float* s2  = s1 + 256;
    k_scores<<<NB * NN + NB, 256, 0, stream>>>(x, nb, W1, W2, s1, s2);
    k_adj<<<NB * NC, 256, 0, stream>>>(x, nb, s1, s2, adj, hws, nullptr);
    k_gemm_f32<<<256, 256, 0, stream>>>(hws, x, Wc, out);
  }
}

// Round 3
// 112.356 us; speedup vs baseline: 1.6966x; 1.2413x over previous
//
#include <hip/hip_runtime.h>
#include <hip/hip_bf16.h>
#include <math.h>

// B=256, C=4, N=64, F=256, OC=8, OF=256
// d_out = out (256*2048 f32) then adj (256*4*256*256 f32).

typedef __bf16 bf16x8 __attribute__((ext_vector_type(8)));
typedef __bf16 bf16x4 __attribute__((ext_vector_type(4)));
typedef float f32x4 __attribute__((ext_vector_type(4)));

#define NB 256
#define NC 4
#define NN 64
#define NF 256
#define NO 2048

// ---------------- Kernel 1: s1[b], s2[b,n] ----------------
__global__ __launch_bounds__(256) void k_scores(
    const float* __restrict__ x, const float* __restrict__ nb,
    const float* __restrict__ W1, const float* __restrict__ W2,
    float* __restrict__ s1, float* __restrict__ s2)
{
  __shared__ float red[4];
  int t = threadIdx.x;
  int gid = blockIdx.x;
  float val;
  if (gid < NB * NN) {
    float w = W2[t] + W2[256 + t] + W2[512 + t] + W2[768 + t];
    const float* p = nb + (size_t)gid * 1024;
    val = w * (p[t] + p[256 + t] + p[512 + t] + p[768 + t]);
  } else {
    int b = gid - NB * NN;
    float w = W1[t] + W1[256 + t] + W1[512 + t] + W1[768 + t];
    const float* p = x + (size_t)b * 1024;
    val = w * (p[t] + p[256 + t] + p[512 + t] + p[768 + t]);
  }
  for (int off = 32; off > 0; off >>= 1) val += __shfl_down(val, off);
  int wid = t >> 6;
  if ((t & 63) == 0) red[wid] = val;
  __syncthreads();
  if (t == 0) {
    float s = red[0] + red[1] + red[2] + red[3];
    if (gid < NB * NN) s2[gid] = s;
    else s1[gid - NB * NN] = s;
  }
}

// ---------------- Kernel 2: bf16 pre-conversion ----------------
__global__ __launch_bounds__(256) void k_cvt(
    const float* __restrict__ Wc, const float* __restrict__ x,
    __hip_bfloat16* __restrict__ Wcb, __hip_bfloat16* __restrict__ zbf)
{
  int idx = blockIdx.x * 256 + threadIdx.x;
  if (idx < 1048576) {
    float4 v = ((const float4*)Wc)[idx];
    bf16x4 o = { (__bf16)v.x, (__bf16)v.y, (__bf16)v.z, (__bf16)v.w };
    ((bf16x4*)Wcb)[idx] = o;
  } else {
    int i = idx - 1048576;
    int e = i * 4;
    int b = e >> 10, r = e & 1023;
    float4 v = ((const float4*)x)[i];
    bf16x4 o = { (__bf16)v.x, (__bf16)v.y, (__bf16)v.z, (__bf16)v.w };
    *(bf16x4*)(zbf + (size_t)b * 2048 + 1024 + r) = o;
  }
}

// ---------------- Kernel 3: adj + h ----------------
// One block per (b,c). fadj_sym symmetric -> column normalizer == row sum.
// Wave w owns rows w*64..w*64+63; lane l owns cols 4l..4l+3.
__global__ __launch_bounds__(256) void k_adj(
    const float* __restrict__ x, const float* __restrict__ nb,
    const float* __restrict__ s1, const float* __restrict__ s2,
    float* __restrict__ adj, float* __restrict__ hf,
    __hip_bfloat16* __restrict__ zbf)
{
  __shared__ float xs[256], ns[256], invs[256], wsh[64];
  __shared__ float part[4][256];
  int t = threadIdx.x;
  int w = t >> 6, l = t & 63;
  int blk = blockIdx.x;
  int b = blk >> 2, c = blk & 3;

  if (t < 64) {
    float v = s1[b] * s2[b * 64 + t];
    float m = v;
    for (int off = 32; off > 0; off >>= 1) m = fmaxf(m, __shfl_xor(m, off));
    float e = expf(v - m);
    float s = e;
    for (int off = 32; off > 0; off >>= 1) s += __shfl_xor(s, off);
    wsh[t] = e / s;
  }
  __syncthreads();

  // nw[t] = sum_n w[n] * neighbor[b,n,c,t]
  float acc = 0.f;
  const float* pb = nb + (size_t)b * 65536 + c * 256 + t;
  #pragma unroll 8
  for (int n = 0; n < 64; ++n) acc = fmaf(wsh[n], pb[(size_t)n * 1024], acc);
  ns[t] = acc;
  xs[t] = x[(size_t)blk * 256 + t];
  __syncthreads();

  int j0 = l * 4;
  float4 xv = *(const float4*)&xs[j0];
  float4 nv = *(const float4*)&ns[j0];
  int i0 = w * 64;

  // pass 1: column sums of |g| (symmetric => equals row sums)
  float4 cs = {0.f, 0.f, 0.f, 0.f};
  #pragma unroll 4
  for (int ii = 0; ii < 64; ++ii) {
    int i = i0 + ii;
    float xi = xs[i], ni = ns[i];
    float v0 = fmaf(xi, nv.x, xv.x * ni);
    float v1 = fmaf(xi, nv.y, xv.y * ni);
    float v2 = fmaf(xi, nv.z, xv.z * ni);
    float v3 = fmaf(xi, nv.w, xv.w * ni);
    float r0 = __builtin_amdgcn_sqrtf(fmaxf(fabsf(v0), 1e-8f));
    float r1 = __builtin_amdgcn_sqrtf(fmaxf(fabsf(v1), 1e-8f));
    float r2 = __builtin_amdgcn_sqrtf(fmaxf(fabsf(v2), 1e-8f));
    float r3 = __builtin_amdgcn_sqrtf(fmaxf(fabsf(v3), 1e-8f));
    cs.x += (v0 != 0.f) ? r0 : 0.f;
    cs.y += (v1 != 0.f) ? r1 : 0.f;
    cs.z += (v2 != 0.f) ? r2 : 0.f;
    cs.w += (v3 != 0.f) ? r3 : 0.f;
  }
  *(float4*)&part[w][j0] = cs;
  __syncthreads();
  invs[t] = 1.f / (part[0][t] + part[1][t] + part[2][t] + part[3][t] + 1e-7f);
  __syncthreads();

  float4 iv = *(const float4*)&invs[j0];
  float4 ha = {0.f, 0.f, 0.f, 0.f};
  float* ab = adj + (size_t)blk * 65536;
  #pragma unroll 4
  for (int ii = 0; ii < 64; ++ii) {
    int i = i0 + ii;
    float xi = xs[i], ni = ns[i];
    float pix = invs[i] * xi;
    float v0 = fmaf(xi, nv.x, xv.x * ni);
    float v1 = fmaf(xi, nv.y, xv.y * ni);
    float v2 = fmaf(xi, nv.z, xv.z * ni);
    float v3 = fmaf(xi, nv.w, xv.w * ni);
    float g0 = (v0 != 0.f) ? copysignf(__builtin_amdgcn_sqrtf(fmaxf(fabsf(v0), 1e-8f)), v0) : 0.f;
    float g1 = (v1 != 0.f) ? copysignf(__builtin_amdgcn_sqrtf(fmaxf(fabsf(v1), 1e-8f)), v1) : 0.f;
    float g2 = (v2 != 0.f) ? copysignf(__builtin_amdgcn_sqrtf(fmaxf(fabsf(v2), 1e-8f)), v2) : 0.f;
    float g3 = (v3 != 0.f) ? copysignf(__builtin_amdgcn_sqrtf(fmaxf(fabsf(v3), 1e-8f)), v3) : 0.f;
    f32x4 o = { g0 * iv.x, g1 * iv.y, g2 * iv.z, g3 * iv.w };
    __builtin_nontemporal_store(o, (f32x4*)&ab[(size_t)i * 256 + j0]);
    ha.x = fmaf(g0, pix, ha.x);
    ha.y = fmaf(g1, pix, ha.y);
    ha.z = fmaf(g2, pix, ha.z);
    ha.w = fmaf(g3, pix, ha.w);
  }
  __syncthreads();
  *(float4*)&part[w][j0] = ha;
  __syncthreads();
  float hsum = part[0][t] + part[1][t] + part[2][t] + part[3][t];
  if (zbf) zbf[(size_t)b * 2048 + c * 256 + t] = __float2bfloat16(hsum);
  else     hf[(size_t)blk * 256 + t] = hsum;
}

// ---------------- Kernel 4: out = Z @ Wc^T (bf16 MFMA) ----------------
// 512 blocks: bm in [0,8) m-tile 32, bn in [0,64) n-tile 32.
// Wave w: m0 = bm*32 + (w&1)*16, n0 = bn*32 + (w>>1)*16; 16x16 tile, 2-deep K-ILP.
__global__ __launch_bounds__(256) void k_gemm(
    const __hip_bfloat16* __restrict__ zb, const __hip_bfloat16* __restrict__ Wcb,
    float* __restrict__ out)
{
  int tid = threadIdx.x;
  int wave = tid >> 6, lane = tid & 63;
  int g = lane >> 4, r = lane & 15;
  int bm = blockIdx.x & 7, bn = blockIdx.x >> 3;
  int m0 = bm * 32 + (wave & 1) * 16;
  int n0 = bn * 32 + (wave >> 1) * 16;

  const bf16x8* pa = (const bf16x8*)(zb  + (size_t)(m0 + r) * 2048 + g * 8);
  const bf16x8* pw = (const bf16x8*)(Wcb + (size_t)(n0 + r) * 2048 + g * 8);

  f32x4 acc0 = {0.f, 0.f, 0.f, 0.f}, acc1 = {0.f, 0.f, 0.f, 0.f};
  #pragma unroll 4
  for (int ks = 0; ks < 64; ks += 2) {
    bf16x8 a0 = pa[ks * 4];
    bf16x8 b0 = pw[ks * 4];
    bf16x8 a1 = pa[ks * 4 + 4];
    bf16x8 b1 = pw[ks * 4 + 4];
    acc0 = __builtin_amdgcn_mfma_f32_16x16x32_bf16(a0, b0, acc0, 0, 0, 0);
    acc1 = __builtin_amdgcn_mfma_f32_16x16x32_bf16(a1, b1, acc1, 0, 0, 0);
  }
  acc0 += acc1;
  #pragma unroll
  for (int q = 0; q < 4; ++q) {
    int row = m0 + g * 4 + q;
    __builtin_nontemporal_store(acc0[q], &out[(size_t)row * 2048 + n0 + r]);
  }
}

// ---------------- Fallback GEMM (f32 inputs, cvt in loop) ----------------
__device__ inline bf16x8 cvt8_p(const float* p) {
  const float4* q = reinterpret_cast<const float4*>(p);
  float4 a = q[0], bq = q[1];
  bf16x8 r;
  r[0] = (__bf16)a.x;  r[1] = (__bf16)a.y;  r[2] = (__bf16)a.z;  r[3] = (__bf16)a.w;
  r[4] = (__bf16)bq.x; r[5] = (__bf16)bq.y; r[6] = (__bf16)bq.z; r[7] = (__bf16)bq.w;
  return r;
}

__global__ __launch_bounds__(256) void k_gemm_f32(
    const float* __restrict__ h, const float* __restrict__ x,
    const float* __restrict__ Wc, float* __restrict__ out)
{
  int tid = threadIdx.x;
  int wave = tid >> 6, lane = tid & 63;
  int g = lane >> 4, r = lane & 15;
  int bm = blockIdx.x & 3, bn = blockIdx.x >> 2;
  int m0 = bm * 64 + wave * 16;
  int n0 = bn * 32;
  int arow = m0 + r;
  int koff = g * 8;

  const float* za = h + (size_t)arow * 1024 + koff;
  const float* zb = x + (size_t)arow * 1024 + koff;
  const float* w0 = Wc + (size_t)(n0 + r) * 2048 + koff;
  const float* w1 = Wc + (size_t)(n0 + 16 + r) * 2048 + koff;

  f32x4 acc0 = {0.f, 0.f, 0.f, 0.f}, acc1 = {0.f, 0.f, 0.f, 0.f};
  #pragma unroll 4
  for (int ks = 0; ks < 32; ++ks) {
    bf16x8 a  = cvt8_p(za + ks * 32);
    bf16x8 b0 = cvt8_p(w0 + ks * 32);
    bf16x8 b1 = cvt8_p(w1 + ks * 32);
    acc0 = __builtin_amdgcn_mfma_f32_16x16x32_bf16(a, b0, acc0, 0, 0, 0);
    acc1 = __builtin_amdgcn_mfma_f32_16x16x32_bf16(a, b1, acc1, 0, 0, 0);
  }
  #pragma unroll 4
  for (int ks = 0; ks < 32; ++ks) {
    bf16x8 a  = cvt8_p(zb + ks * 32);
    bf16x8 b0 = cvt8_p(w0 + 1024 + ks * 32);
    bf16x8 b1 = cvt8_p(w1 + 1024 + ks * 32);
    acc0 = __builtin_amdgcn_mfma_f32_16x16x32_bf16(a, b0, acc0, 0, 0, 0);
    acc1 = __builtin_amdgcn_mfma_f32_16x16x32_bf16(a, b1, acc1, 0, 0, 0);
  }
  #pragma unroll
  for (int q = 0; q < 4; ++q) {
    int row = m0 + g * 4 + q;
    out[(size_t)row * 2048 + n0 + r]      = acc0[q];
    out[(size_t)row * 2048 + n0 + 16 + r] = acc1[q];
  }
}

extern "C" void kernel_launch(void* const* d_in, const int* in_sizes, int n_in,
                              void* d_out, int out_size, void* d_ws, size_t ws_size,
                              hipStream_t stream) {
  const float* x  = (const float*)d_in[0];
  const float* nb = (const float*)d_in[1];
  const float* W1 = (const float*)d_in[2];
  const float* W2 = (const float*)d_in[3];
  const float* Wc = (const float*)d_in[4];
  float* out = (float*)d_out;
  float* adj = out + (size_t)NB * NO;

  char* ws = (char*)d_ws;
  const size_t ZBF_B = 1048576;       // 256*2048 bf16
  const size_t WCB_B = 8388608;       // 2048*2048 bf16
  bool fast = ws_size >= ZBF_B + WCB_B + 66560;

  if (fast) {
    __hip_bfloat16* zbf = (__hip_bfloat16*)ws;
    __hip_bfloat16* Wcb = (__hip_bfloat16*)(ws + ZBF_B);
    float* s1 = (float*)(ws + ZBF_B + WCB_B);
    float* s2 = s1 + 256;
    k_scores<<<NB * NN + NB, 256, 0, stream>>>(x, nb, W1, W2, s1, s2);
    k_cvt<<<4352, 256, 0, stream>>>(Wc, x, Wcb, zbf);
    k_adj<<<NB * NC, 256, 0, stream>>>(x, nb, s1, s2, adj, nullptr, zbf);
    k_gemm<<<512, 256, 0, stream>>>(zbf, Wcb, out);
  } else {
    float* hws = (float*)d_ws;
    float* s1  = hws + 262144;
    float* s2  = s1 + 256;
    k_scores<<<NB * NN + NB, 256, 0, stream>>>(x, nb, W1, W2, s1, s2);
    k_adj<<<NB * NC, 256, 0, stream>>>(x, nb, s1, s2, adj, hws, nullptr);
    k_gemm_f32<<<256, 256, 0, stream>>>(hws, x, Wc, out);
  }
}